// Round 4
// baseline (520.170 us; speedup 1.0000x reference)
//
#include <hip/hip_runtime.h>

#define TAU 0.2f
#define VTH 0.3f

typedef float v4f __attribute__((ext_vector_type(4)));  // native clang vector
// (required by __builtin_nontemporal_store; HIP float4 is rejected).

#define BLOCKS 1024         // 4 blocks/CU resident; grid-stride like a copy kernel
#define THREADS 256
#define PX_PER_ITER 4       // 4 pixels = 8 float4 = 128 B per thread per iter
#define ITERS 4             // 4194304 px / (1024*256*4) = 4, exact

// x: [B,C,H,W,T] fp32, T=8 innermost/contiguous. Thread owns 4 consecutive
// pixels per iteration; double-buffered so the next iteration's 8 dwordx4
// loads are in flight while this iteration computes + nt-stores. No LDS, no
// barriers (R3 proved lane-coalescing is not the limiter; MLP is the theory).
__global__ __launch_bounds__(256) void LIFSpike_73864847556979_kernel(
    const float* __restrict__ x, float* __restrict__ out) {
    const int tid = blockIdx.x * THREADS + threadIdx.x;
    const size_t nthreads = (size_t)BLOCKS * THREADS;  // 262144

    const v4f* __restrict__ xin = (const v4f*)x;
    v4f* __restrict__ xout = (v4f*)out;

    v4f cur[8], nxt[8];
    size_t base = (size_t)tid * 8;  // f4 index; thread spans 128 B contiguous

#pragma unroll
    for (int j = 0; j < 8; ++j) cur[j] = xin[base + j];

#pragma unroll 1
    for (int it = 0; it < ITERS; ++it) {
        const size_t nbase = base + nthreads * 8;
        if (it + 1 < ITERS) {
            // Prefetch next iteration: 8 independent dwordx4 in flight
            // during this iteration's compute + stores.
#pragma unroll
            for (int j = 0; j < 8; ++j) nxt[j] = xin[nbase + j];
        }
#pragma unroll
        for (int p = 0; p < PX_PER_ITER; ++p) {
            v4f lo = cur[p * 2], hi = cur[p * 2 + 1];
            float v[8] = {lo.x, lo.y, lo.z, lo.w, hi.x, hi.y, hi.z, hi.w};
            float r[8];
            float u = 0.0f, o = 0.0f;
#pragma unroll
            for (int k = 0; k < 8; ++k) {
                u = TAU * u * (1.0f - o) + v[k];
                o = (u > VTH) ? 1.0f : 0.0f;
                r[k] = o;
            }
            v4f ro = {r[0], r[1], r[2], r[3]};
            v4f rh = {r[4], r[5], r[6], r[7]};
            // Output is write-once, never re-read: keep it out of L2/L3 so
            // the input stays resident.
            __builtin_nontemporal_store(ro, &xout[base + p * 2]);
            __builtin_nontemporal_store(rh, &xout[base + p * 2 + 1]);
        }
#pragma unroll
        for (int j = 0; j < 8; ++j) cur[j] = nxt[j];
        base = nbase;
    }
}

extern "C" void kernel_launch(void* const* d_in, const int* in_sizes, int n_in,
                              void* d_out, int out_size, void* d_ws, size_t ws_size,
                              hipStream_t stream) {
    const float* x = (const float*)d_in[0];
    float* out = (float*)d_out;
    // 32*128*32*32 = 4194304 pixels == BLOCKS*THREADS*PX_PER_ITER*ITERS, exact.
    LIFSpike_73864847556979_kernel<<<BLOCKS, THREADS, 0, stream>>>(x, out);
}

// Round 5
// 231.828 us; speedup vs baseline: 2.2438x; 2.2438x over previous
//
#include <hip/hip_runtime.h>

#define TAU 0.2f
#define VTH 0.3f

typedef float v4f __attribute__((ext_vector_type(4)));

#define BLOCKS 2048     // 8 blocks/CU exactly -> 32 waves/CU resident
#define THREADS 256
#define NPIX (32 * 128 * 32 * 32)          // 4194304
#define NTH (BLOCKS * THREADS)             // 524288 -> 8 pixels/thread
#define ITERS (NPIX / NTH)                 // 8, exact

// Persistent grid-stride version of the R0 pattern. Per iteration a thread
// owns one pixel (32 B): lanes stride 32 B -> each load/store instruction
// pair covers a fully dense 2 KiB span. Stores are NORMAL (cached): L2 must
// write-combine the two half-line store instructions — R4 proved `nt` on
// non-instruction-dense stores causes 3x HBM write amplification (RMW).
// Next iteration's loads are prefetched during current compute+store.
__global__ __launch_bounds__(256) void LIFSpike_73864847556979_kernel(
    const float* __restrict__ x, float* __restrict__ out) {
    const int tid = blockIdx.x * THREADS + threadIdx.x;

    const v4f* __restrict__ xin = (const v4f*)x;
    v4f* __restrict__ xout = (v4f*)out;

    size_t base = (size_t)tid * 2;           // f4 index of this thread's pixel
    const size_t stride = (size_t)NTH * 2;   // f4 stride per iteration

    v4f a = xin[base];
    v4f b = xin[base + 1];

#pragma unroll 1
    for (int it = 0; it < ITERS; ++it) {
        v4f na, nb;
        const size_t nbase = base + stride;
        if (it + 1 < ITERS) {   // prefetch next pixel while computing current
            na = xin[nbase];
            nb = xin[nbase + 1];
        }

        float v[8] = {a.x, a.y, a.z, a.w, b.x, b.y, b.z, b.w};
        float r[8];
        float u = 0.0f, o = 0.0f;
#pragma unroll
        for (int k = 0; k < 8; ++k) {
            u = TAU * u * (1.0f - o) + v[k];
            o = (u > VTH) ? 1.0f : 0.0f;
            r[k] = o;
        }
        xout[base] = (v4f){r[0], r[1], r[2], r[3]};
        xout[base + 1] = (v4f){r[4], r[5], r[6], r[7]};

        a = na;
        b = nb;
        base = nbase;
    }
}

extern "C" void kernel_launch(void* const* d_in, const int* in_sizes, int n_in,
                              void* d_out, int out_size, void* d_ws, size_t ws_size,
                              hipStream_t stream) {
    const float* x = (const float*)d_in[0];
    float* out = (float*)d_out;
    // NPIX == BLOCKS*THREADS*ITERS exactly (4194304 = 2048*256*8).
    LIFSpike_73864847556979_kernel<<<BLOCKS, THREADS, 0, stream>>>(x, out);
}